// Round 10
// baseline (106.211 us; speedup 1.0000x reference)
//
#include <hip/hip_runtime.h>

// CMDNet_58274116272706 — B=16384, NR=64, NT=32, M=4, NITER=64.
// Phase 1: HH = Ht^T Ht per batch via f16 MFMA (Gram trick: A-frag == B-frag),
//          yH = y^T Ht in f32 VALU. Gram output redistributed into MFMA
//          B-fragment layout (HH symmetric -> B[k][j] slices by hi-exchange).
// Phase 2: 64 gradient steps. 4 batches/wave, 2/lane (lane (j,hi) owns
//          bA=c0+2hi, bB=bA+1). R10: matvec xHH = xt·HH via
//          v_mfma_f32_32x32x16_f16 with A-rows replicated (= xt) — every
//          lane gets xHH[lane&31] in C[0]; 8 MFMAs/iter on the idle matrix
//          pipe replace 32 fdot2 (64 VALU-cyc) and shorten the dep chain.
//          Input k-layout (k=(l>>5)*8+e for A and B) verified by the Gram
//          phase itself. xt broadcast through f16 LDS; taui/delta via
//          v_readlane; softmax exp2-domain WITH max-sub (R5: removing NaNs).
// amdgpu_waves_per_eu(4,4): grid = 4 blocks/CU = 4 waves/SIMD max (R4/R8:
// chasing 8 waves spills catastrophically; 4 is the operating point).

#define NRr 64
#define NTt 32
#define NITER 64
#define B_TOTAL 16384

using f16x8  = __attribute__((ext_vector_type(8))) _Float16;
using u32x4  = __attribute__((ext_vector_type(4))) unsigned int;
using f32x16 = __attribute__((ext_vector_type(16))) float;

static __device__ __forceinline__ uint32_t pk16(float a, float b) {
    union { _Float16 h[2]; uint32_t u; } x;
    x.h[0] = (_Float16)a; x.h[1] = (_Float16)b;   // RNE
    return x.u;
}

static __device__ __forceinline__ f16x8 mk8(uint32_t a, uint32_t b,
                                            uint32_t c, uint32_t d) {
    u32x4 t; t[0] = a; t[1] = b; t[2] = c; t[3] = d;
    return __builtin_bit_cast(f16x8, t);
}

static __device__ __forceinline__ float exp2fast(float x) {
#if __has_builtin(__builtin_amdgcn_exp2f)
    return __builtin_amdgcn_exp2f(x);
#else
    return exp2f(x);
#endif
}

static __device__ __forceinline__ float rdlane(float v, int lane) {
    return __builtin_bit_cast(float,
        __builtin_amdgcn_readlane(__builtin_bit_cast(int, v), lane));
}

static __device__ __forceinline__ float rfl(float v) {
    return __builtin_bit_cast(float,
        __builtin_amdgcn_readfirstlane(__builtin_bit_cast(int, v)));
}

static __device__ __forceinline__ uint32_t shflx32(uint32_t v) {
    return (uint32_t)__shfl_xor((int)v, 32, 64);
}

// Gram fragment + y-partial for one batch. ap[2g+c2] = f16 pair of
// HH rows (8g+4hi+2c2, +1) at column j; ypart = y·H over this lane's ks.
static __device__ __forceinline__ void gram_one(
    const float* __restrict__ hp, const float* __restrict__ ypt,
    const int hi, uint32_t ap[8], float& ypart_out)
{
    f32x16 acc = {};
    float  ypart = 0.f;
#pragma unroll
    for (int kc = 0; kc < 4; ++kc) {
        const int kb = kc * 16 + hi * 8;      // this lane's 8 k values
        float h[8];
#pragma unroll
        for (int e = 0; e < 8; ++e) h[e] = hp[(size_t)(kb + e) * NTt];
        const float4 ya = *(const float4*)(ypt + kb);
        const float4 yb = *(const float4*)(ypt + kb + 4);
        ypart += h[0]*ya.x + h[1]*ya.y + h[2]*ya.z + h[3]*ya.w
               + h[4]*yb.x + h[5]*yb.y + h[6]*yb.z + h[7]*yb.w;
        f16x8 fa;
#pragma unroll
        for (int e = 0; e < 8; ++e) fa[e] = (_Float16)h[e];
        // A-frag == B-frag: Gram product is k-permutation-insensitive.
        acc = __builtin_amdgcn_mfma_f32_32x32x16_f16(fa, fa, acc, 0, 0, 0);
    }
    // C layout: col=lane&31, row=(r&3)+8*(r>>2)+4*hi. Pack row pairs.
#pragma unroll
    for (int g = 0; g < 4; ++g) {
        ap[2*g+0] = pk16(acc[4*g+0], acc[4*g+1]);
        ap[2*g+1] = pk16(acc[4*g+2], acc[4*g+3]);
    }
    ypart_out = ypart;
}

__global__ __launch_bounds__(256)
__attribute__((amdgpu_waves_per_eu(4, 4)))
void cmdnet_kernel(
    const float* __restrict__ yt,     // [B,64]
    const float* __restrict__ Ht,     // [B,64,32]
    const float* __restrict__ sig0,   // [B]
    const float* __restrict__ mm,     // [4]
    const float* __restrict__ alpha,  // [4]
    const float* __restrict__ taui,   // [65]
    const float* __restrict__ delta,  // [64]
    float* __restrict__ out)          // ft [B,32,4] then xt [B,32]
{
    __shared__ __align__(16) _Float16 xtsh[4][4][32];  // [wave][batch-slot][nt]

    const int tid = threadIdx.x;
    const int w   = tid >> 6;                 // wave in block
    const int l   = tid & 63;                 // lane
    const int j   = l & 31;                   // nt / matrix column
    const int hi  = l >> 5;                   // half-wave id
    const int c0  = (blockIdx.x * 4 + w) * 4; // wave's 4 batches

    // Per-iteration scalars parked in lane-indexed VGPRs (readlane in loop)
    const float vta = fabsf(taui[l]);         // |taui[it]| for it = lane
    const float vd  = delta[l];               // delta[it]

    const size_t hstride = (size_t)NRr * NTt;

    // ---------------- Phase 1: Gram -> B-fragments, yH ---------------------
    // bff[c][m] = B-frag for batch c0+c, K-half m: lane l supplies
    // B[k_int=(l>>5)*8+e][col=l&31] = HH[m*16 + hi*8 + e][j]  (HH symmetric).
    f16x8 bff[4][2];
    float ysum[4];
#pragma unroll
    for (int c = 0; c < 4; ++c) {
        uint32_t ap[8];
        float yp;
        gram_one(Ht + (size_t)(c0 + c) * hstride + j,
                 yt + (size_t)(c0 + c) * NRr, hi, ap, yp);
        // hi=0 holds row-pairs {0-1,2-3}(ap0,1) {8-9,10-11}(ap2,3)
        //                      {16-17,18-19}(ap4,5) {24-25,26-27}(ap6,7)
        // hi=1 holds           {4-5,6-7}    {12-13,14-15}
        //                      {20-21,22-23}{28-29,30-31}
        const uint32_t r0 = shflx32(hi ? ap[0] : ap[2]);  // 4-5  / 8-9
        const uint32_t r1 = shflx32(hi ? ap[1] : ap[3]);  // 6-7  / 10-11
        const uint32_t r2 = shflx32(hi ? ap[4] : ap[6]);  // 20-21/ 24-25
        const uint32_t r3 = shflx32(hi ? ap[5] : ap[7]);  // 22-23/ 26-27
        // m0 rows: hi=0 -> 0-7, hi=1 -> 8-15 ; m1 rows: 16-23 / 24-31
        bff[c][0] = hi ? mk8(r0, r1, ap[2], ap[3]) : mk8(ap[0], ap[1], r0, r1);
        bff[c][1] = hi ? mk8(r2, r3, ap[6], ap[7]) : mk8(ap[4], ap[5], r2, r3);
        ysum[c] = yp + __shfl_xor(yp, 32, 64);
    }
    const float yHA_v = hi ? ysum[2] : ysum[0];
    const float yHB_v = hi ? ysum[3] : ysum[1];

    const int bA = c0 + 2*hi;
    const int bB = bA + 1;
    const float sgA = sig0[bA], sgB = sig0[bB];
    const float sig2A = sgA * sgA, sig2B = sgB * sgB;

    const float4 mv = *(const float4*)mm;
    const float4 av = *(const float4*)alpha;
    const float m0 = rfl(mv.x), m1 = rfl(mv.y), m2 = rfl(mv.z), m3 = rfl(mv.w);
    // exp2-domain softmax scores: (log2 a + G*log2e)*scale
    const float la0 = rfl(__log2f(av.x)), la1 = rfl(__log2f(av.y));
    const float la2 = rfl(__log2f(av.z)), la3 = rfl(__log2f(av.w));

    const float L2E  = 1.4426950408889634f;
    const float NL2E = -1.4426950408889634f;

    _Float16* xwA = &xtsh[w][2*hi][j];        // own batch slots
    _Float16* xwB = &xtsh[w][2*hi+1][j];
    // A-frag source: per slot c, uint4 index c*4 + m*2 + hi (16B each)
    const u32x4* xs = (const u32x4*)&xtsh[w][0][0];
    const int afb = hi;                        // base offset within slot

    const f32x16 zc = {};                      // hoisted MFMA C seed

    float GA0 = 0.f, GA1 = 0.f, GA2 = 0.f, GA3 = 0.f;
    float GB0 = 0.f, GB1 = 0.f, GB2 = 0.f, GB3 = 0.f;

    // ---------------- Phase 2: 64 descent steps ----------------------------
    for (int it = 0; it < NITER; ++it) {
        const float ta  = rdlane(vta, it);
        const float d   = rdlane(vd,  it);
        const float sc  = (it == 0) ? 1.0f : ta;  // first layer: scale 1
        const float scL = sc * L2E;
        const float tad = ta * d;
        const float c1A = d * sig2A, c1B = d * sig2B;
        const float ls0 = la0 * sc, ls1 = la1 * sc,
                    ls2 = la2 * sc, ls3 = la3 * sc;

        // softmax over M=4, exp2 domain, WITH max-subtraction
        const float sA0 = fmaf(GA0, scL, ls0), sA1 = fmaf(GA1, scL, ls1);
        const float sA2 = fmaf(GA2, scL, ls2), sA3 = fmaf(GA3, scL, ls3);
        const float sB0 = fmaf(GB0, scL, ls0), sB1 = fmaf(GB1, scL, ls1);
        const float sB2 = fmaf(GB2, scL, ls2), sB3 = fmaf(GB3, scL, ls3);
        const float mxA = fmaxf(fmaxf(fmaxf(sA0, sA1), sA2), sA3);  // v_max3
        const float mxB = fmaxf(fmaxf(fmaxf(sB0, sB1), sB2), sB3);
        const float eA0 = exp2fast(sA0 - mxA), eA1 = exp2fast(sA1 - mxA);
        const float eA2 = exp2fast(sA2 - mxA), eA3 = exp2fast(sA3 - mxA);
        const float eB0 = exp2fast(sB0 - mxB), eB1 = exp2fast(sB1 - mxB);
        const float eB2 = exp2fast(sB2 - mxB), eB3 = exp2fast(sB3 - mxB);
        const float ZA = (eA0 + eA1) + (eA2 + eA3);
        const float ZB = (eB0 + eB1) + (eB2 + eB3);
        const float RA = __builtin_amdgcn_rcpf(ZA);
        const float RB = __builtin_amdgcn_rcpf(ZB);
        const float SA = fmaf(eA0, m0, fmaf(eA1, m1, fmaf(eA2, m2, eA3 * m3)));
        const float SB = fmaf(eB0, m0, fmaf(eB1, m1, fmaf(eB2, m2, eB3 * m3)));
        const float xtA = SA * RA;
        const float xtB = SB * RB;

        // broadcast xt within the wave (same-wave DS ops are in-order)
        *xwA = (_Float16)xtA;
        *xwB = (_Float16)xtB;
        asm volatile("" ::: "memory");

        // barrier exps are independent of the LDS round-trip — overlap it
        const float enA0 = exp2fast(GA0 * NL2E), enA1 = exp2fast(GA1 * NL2E);
        const float enA2 = exp2fast(GA2 * NL2E), enA3 = exp2fast(GA3 * NL2E);
        const float enB0 = exp2fast(GB0 * NL2E), enB1 = exp2fast(GB1 * NL2E);
        const float enB2 = exp2fast(GB2 * NL2E), enB3 = exp2fast(GB3 * NL2E);

        // matvec per batch slot: A rows replicated = xt_c -> D[*][j] = xHH_c[j]
        float xh[4];
#pragma unroll
        for (int c = 0; c < 4; ++c) {
            const f16x8 a0 = __builtin_bit_cast(f16x8, xs[c*4 + 0*2 + afb]);
            const f16x8 a1 = __builtin_bit_cast(f16x8, xs[c*4 + 1*2 + afb]);
            f32x16 acc = __builtin_amdgcn_mfma_f32_32x32x16_f16(
                             a0, bff[c][0], zc, 0, 0, 0);
            acc = __builtin_amdgcn_mfma_f32_32x32x16_f16(
                             a1, bff[c][1], acc, 0, 0, 0);
            xh[c] = acc[0];                    // all 16 C regs identical
        }
        asm volatile("" ::: "memory");

        const float pA = hi ? xh[2] : xh[0];   // own bA result
        const float pB = hi ? xh[3] : xh[1];   // own bB result

        const float qdA = pA - yHA_v;
        const float qdB = pB - yHB_v;
        const float tqA = tad * qdA * RA;      // folds ta, delta, 1/Z
        const float tqB = tad * qdB * RB;

        // G' = (G - c1) + c1*exp(-G) - tq * e_i * (m_i - xt)
        GA0 = fmaf(-tqA, eA0 * (m0 - xtA), fmaf(c1A, enA0, GA0 - c1A));
        GA1 = fmaf(-tqA, eA1 * (m1 - xtA), fmaf(c1A, enA1, GA1 - c1A));
        GA2 = fmaf(-tqA, eA2 * (m2 - xtA), fmaf(c1A, enA2, GA2 - c1A));
        GA3 = fmaf(-tqA, eA3 * (m3 - xtA), fmaf(c1A, enA3, GA3 - c1A));
        GB0 = fmaf(-tqB, eB0 * (m0 - xtB), fmaf(c1B, enB0, GB0 - c1B));
        GB1 = fmaf(-tqB, eB1 * (m1 - xtB), fmaf(c1B, enB1, GB1 - c1B));
        GB2 = fmaf(-tqB, eB2 * (m2 - xtB), fmaf(c1B, enB2, GB2 - c1B));
        GB3 = fmaf(-tqB, eB3 * (m3 - xtB), fmaf(c1B, enB3, GB3 - c1B));
    }

    // ---------------- Final layer: softmax + soft symbol, store ------------
    // scores: (ln a + G)*ta == (log2 a + G*log2e)*ta in exp2 domain
    const float tap = fabsf(taui[NITER]);
#pragma unroll
    for (int s = 0; s < 2; ++s) {
        const float G0 = s ? GB0 : GA0, G1 = s ? GB1 : GA1;
        const float G2 = s ? GB2 : GA2, G3 = s ? GB3 : GA3;
        const int   bm = s ? bB : bA;
        const float w0 = fmaf(G0, L2E, la0) * tap;
        const float w1 = fmaf(G1, L2E, la1) * tap;
        const float w2 = fmaf(G2, L2E, la2) * tap;
        const float w3 = fmaf(G3, L2E, la3) * tap;
        const float mx = fmaxf(fmaxf(fmaxf(w0, w1), w2), w3);
        const float e0 = exp2fast(w0 - mx), e1 = exp2fast(w1 - mx);
        const float e2 = exp2fast(w2 - mx), e3 = exp2fast(w3 - mx);
        const float Z  = (e0 + e1) + (e2 + e3);
        const float R  = __builtin_amdgcn_rcpf(Z);
        const float f0 = e0 * R, f1 = e1 * R, f2 = e2 * R, f3 = e3 * R;
        const float xt = fmaf(f0, m0, fmaf(f1, m1, fmaf(f2, m2, f3 * m3)));

        float4 f4; f4.x = f0; f4.y = f1; f4.z = f2; f4.w = f3;
        *(float4*)(out + ((size_t)bm * NTt + j) * 4) = f4;
        out[(size_t)B_TOTAL * NTt * 4 + (size_t)bm * NTt + j] = xt;
    }
}

extern "C" void kernel_launch(void* const* d_in, const int* in_sizes, int n_in,
                              void* d_out, int out_size, void* d_ws, size_t ws_size,
                              hipStream_t stream) {
    const float* yt    = (const float*)d_in[0];
    const float* Ht    = (const float*)d_in[1];
    const float* sig0  = (const float*)d_in[2];
    const float* mm    = (const float*)d_in[3];
    const float* alpha = (const float*)d_in[4];
    const float* taui  = (const float*)d_in[5];
    const float* delta = (const float*)d_in[6];
    float* out = (float*)d_out;

    const int blocks = B_TOTAL / 16;  // 16 batches per 256-thread block
    cmdnet_kernel<<<blocks, 256, 0, stream>>>(yt, Ht, sig0, mm, alpha, taui,
                                              delta, out);
}